// Round 7
// baseline (834.299 us; speedup 1.0000x reference)
//
#include <hip/hip_runtime.h>
#include <hip/hip_bf16.h>

// Problem constants (match reference)
#define NN 100000      // nodes
#define FE 512         // in_feats
#define HF 128         // h_feats
#define NE 1600000     // edges
#define NNIE 4         // hops+1

typedef __attribute__((ext_vector_type(8))) __bf16 bf16x8;
typedef __attribute__((ext_vector_type(4))) float f32x4;
typedef __attribute__((ext_vector_type(8))) unsigned short ushort8;

__device__ __forceinline__ unsigned short f2bf(float f) {
    unsigned u = __float_as_uint(f);
    unsigned r = (u + 0x7fffu + ((u >> 16) & 1u)) >> 16;  // RNE
    return (unsigned short)r;
}
__device__ __forceinline__ float b2f(unsigned short u) {
    return __uint_as_float(((unsigned)u) << 16);
}

// z arrays use an XCD-sliced layout: z[slice][node][16], slice = feat >> 4.
// Slice s of any z array is 3.2 MB -> fits one XCD's 4 MB L2.

// ---------------------------------------------------------------------------
// Graph preprocessing
// ---------------------------------------------------------------------------
__global__ __launch_bounds__(256) void k_zero(int* __restrict__ deg,
                                              int* __restrict__ cursor, int n) {
    int i = blockIdx.x * 256 + threadIdx.x;
    if (i < n) { deg[i] = 0; cursor[i] = 0; }
}

__global__ __launch_bounds__(256) void k_count(const int* __restrict__ row,
                                               int* __restrict__ deg, int e) {
    int i = blockIdx.x * 256 + threadIdx.x;
    if (i < e) atomicAdd(&deg[row[i]], 1);
}

// ---- multi-block exclusive scan (3 passes); pass 1 also computes dinv -----
__global__ __launch_bounds__(1024) void k_scan1(const int* __restrict__ cnt,
                                                int* __restrict__ off,
                                                int* __restrict__ bsum,
                                                float* __restrict__ dinv,
                                                int n) {
    __shared__ int wsum[16];
    const int tid = threadIdx.x, lane = tid & 63, wid = tid >> 6;
    const int i = blockIdx.x * 1024 + tid;
    const int v = (i < n) ? cnt[i] : 0;
    if (i < n) dinv[i] = rsqrtf((float)(v + 1));  // +1 self loop
    int x = v;
#pragma unroll
    for (int s = 1; s < 64; s <<= 1) {
        int t = __shfl_up(x, s);
        if (lane >= s) x += t;
    }
    if (lane == 63) wsum[wid] = x;
    __syncthreads();
    if (wid == 0 && lane < 16) {
        int t = wsum[lane];
#pragma unroll
        for (int s = 1; s < 16; s <<= 1) {
            int u = __shfl_up(t, s);
            if (lane >= s) t += u;
        }
        wsum[lane] = t;
    }
    __syncthreads();
    const int wexc = (wid == 0) ? 0 : wsum[wid - 1];
    if (i < n) off[i] = wexc + x - v;  // block-local exclusive
    if (tid == 0) bsum[blockIdx.x] = wsum[15];
}
__global__ __launch_bounds__(1024) void k_scan2(int* __restrict__ bsum, int nb,
                                                int* __restrict__ total_out) {
    __shared__ int wsum[16];
    const int tid = threadIdx.x, lane = tid & 63, wid = tid >> 6;
    const int v = (tid < nb) ? bsum[tid] : 0;
    int x = v;
#pragma unroll
    for (int s = 1; s < 64; s <<= 1) {
        int t = __shfl_up(x, s);
        if (lane >= s) x += t;
    }
    if (lane == 63) wsum[wid] = x;
    __syncthreads();
    if (wid == 0 && lane < 16) {
        int t = wsum[lane];
#pragma unroll
        for (int s = 1; s < 16; s <<= 1) {
            int u = __shfl_up(t, s);
            if (lane >= s) t += u;
        }
        wsum[lane] = t;
    }
    __syncthreads();
    const int wexc = (wid == 0) ? 0 : wsum[wid - 1];
    if (tid < nb) bsum[tid] = wexc + x - v;
    if (tid == 0) *total_out = wsum[15];
}
__global__ __launch_bounds__(256) void k_scan3(int* __restrict__ off,
                                               const int* __restrict__ bsum,
                                               int n) {
    int i = blockIdx.x * 256 + threadIdx.x;
    if (i < n) off[i] += bsum[i >> 10];
}

// fill interleaved (col, weight) edge records
__global__ __launch_bounds__(256) void k_fill(const int* __restrict__ rows,
                                              const int* __restrict__ cols,
                                              const float* __restrict__ dinv,
                                              const int* __restrict__ off,
                                              int* __restrict__ cursor,
                                              int2* __restrict__ es, int e) {
    int i = blockIdx.x * 256 + threadIdx.x;
    if (i < e) {
        int r = rows[i], c = cols[i];
        int pos = off[r] + atomicAdd(&cursor[r], 1);
        es[pos] = make_int2(c, __float_as_int(dinv[r] * dinv[c]));
    }
}

// all weight transposes+cvt in one launch (n-major B^T layouts)
__global__ __launch_bounds__(256) void k_wt_all(
    const float* __restrict__ Wu, const float* __restrict__ Wr,
    const float* __restrict__ Wi, unsigned short* __restrict__ Tu,
    unsigned short* __restrict__ Tr, unsigned short* __restrict__ Ti) {
    int i = blockIdx.x * 256 + threadIdx.x;
    if (i < 65536) {
        int k = i >> 7, n = i & 127;
        Tu[n * 512 + k] = f2bf(Wu[i]);
    } else if (i < 131072) {
        int j = i - 65536;
        int k = j >> 7, n = j & 127;
        Tr[n * 512 + k] = f2bf(Wr[j]);
    } else if (i < 196608) {
        int j = i - 131072;
        int hh = j >> 14, r = j & 16383;
        int k = r >> 7, n = r & 127;
        Ti[hh * 16384 + n * 128 + k] = f2bf(Wi[j]);
    }
}

// ---------------------------------------------------------------------------
// XCD-sliced SpMM (bf16): y[s][i] = dinv[i]^2*z[s][i] + sum_e w_e*z[s][col_e]
// slice = blockIdx % 8 -> round-robin dispatch puts slice s on XCD s, whose
// 3.2 MB z-slice is L2-resident.  Block = 4 waves x (8 nodes x 4 slots x 2
// halves); each lane gathers 16 B; 2-deep unroll; slot-reduce shfl_xor(2|4).
// ---------------------------------------------------------------------------
__global__ __launch_bounds__(256) void k_spmm(
    const unsigned short* __restrict__ z, unsigned short* __restrict__ y,
    const int* __restrict__ off, const int2* __restrict__ es,
    const float* __restrict__ dinv, int n) {
    const int b = blockIdx.x;
    const int slice = b & 7;
    const int chunk = b >> 3;
    const int lane = threadIdx.x & 63;
    const int waveId = threadIdx.x >> 6;
    const int ng = lane >> 3;        // node subgroup 0..7
    const int sl = (lane >> 1) & 3;  // edge slot 0..3
    const int half = lane & 1;       // 8-feat half
    const int node = chunk * 32 + waveId * 8 + ng;
    if (node >= n) return;

    const unsigned short* zs = z + (size_t)slice * n * 16;
    unsigned short* ys = y + (size_t)slice * n * 16;

    float acc[8];
#pragma unroll
    for (int j = 0; j < 8; j++) acc[j] = 0.0f;

    const int p0 = off[node], p1 = off[node + 1];
    int p = p0 + sl;
    for (; p + 4 < p1; p += 8) {  // two edges per slot in flight
        const int2 e0 = es[p], e1 = es[p + 4];
        const ushort8 t0 = *(const ushort8*)(zs + (size_t)e0.x * 16 + 8 * half);
        const ushort8 t1 = *(const ushort8*)(zs + (size_t)e1.x * 16 + 8 * half);
        const float w0 = __int_as_float(e0.y), w1 = __int_as_float(e1.y);
#pragma unroll
        for (int j = 0; j < 8; j++) acc[j] = fmaf(w0, b2f(t0[j]), acc[j]);
#pragma unroll
        for (int j = 0; j < 8; j++) acc[j] = fmaf(w1, b2f(t1[j]), acc[j]);
    }
    if (p < p1) {
        const int2 e0 = es[p];
        const ushort8 t0 = *(const ushort8*)(zs + (size_t)e0.x * 16 + 8 * half);
        const float w0 = __int_as_float(e0.y);
#pragma unroll
        for (int j = 0; j < 8; j++) acc[j] = fmaf(w0, b2f(t0[j]), acc[j]);
    }
    if (sl == 0) {  // self loop: dinv^2 * z[node]
        const float di = dinv[node];
        const ushort8 v = *(const ushort8*)(zs + (size_t)node * 16 + 8 * half);
        const float d2 = di * di;
#pragma unroll
        for (int j = 0; j < 8; j++) acc[j] = fmaf(d2, b2f(v[j]), acc[j]);
    }
    // reduce across the 4 slots (lane bits 1..2)
#pragma unroll
    for (int j = 0; j < 8; j++) {
        acc[j] += __shfl_xor(acc[j], 2);
        acc[j] += __shfl_xor(acc[j], 4);
    }
    if (sl == 0) {
        ushort8 o;
#pragma unroll
        for (int j = 0; j < 8; j++) o[j] = f2bf(acc[j]);
        *(ushort8*)(ys + (size_t)node * 16 + 8 * half) = o;
    }
}

// ---------------------------------------------------------------------------
// Unified-transform GEMM (M x 512 @ 512 x 128, fp32 A) + row-L2-normalize of
// A (epilogue scale) + bias + LayerNorm + ReLU -> bf16 out (sliced layout).
// ---------------------------------------------------------------------------
__global__ __launch_bounds__(256) void gemm_uni(
    const float* __restrict__ A, const unsigned short* __restrict__ Wt,
    const float* __restrict__ bias, const float* __restrict__ g,
    const float* __restrict__ be, unsigned short* __restrict__ out, int M) {
    constexpr int K = FE;
    constexpr int LDT = 72;  // 64 + 8 pad shorts
    __shared__ unsigned short Ast[64][LDT];
    __shared__ unsigned short Bst[128][LDT];
    __shared__ float rn_s[64];

    const int tid = threadIdx.x;
    const int row0 = blockIdx.x * 64;
    const int w = tid >> 6;
    const int lane = tid & 63;
    const int m = lane & 15;
    const int q = lane >> 4;
    const int lrow = tid >> 2;
    const int lq = tid & 3;

    f32x4 acc[8];
#pragma unroll
    for (int t = 0; t < 8; t++) acc[t] = (f32x4){0.f, 0.f, 0.f, 0.f};

    float sumsq = 0.0f;
    const bool arow_ok = (row0 + lrow) < M;

    for (int k0 = 0; k0 < K; k0 += 64) {
        __syncthreads();
#pragma unroll
        for (int oo = 0; oo < 2; oo++) {
            const int o = lq + 4 * oo;
            f32x4 a0 = (f32x4){0.f, 0.f, 0.f, 0.f}, a1 = a0;
            if (arow_ok) {
                const float* Ap =
                    A + (size_t)(row0 + lrow) * K + k0 + 8 * o;
                a0 = *(const f32x4*)Ap;
                a1 = *(const f32x4*)(Ap + 4);
            }
#pragma unroll
            for (int j = 0; j < 4; j++) sumsq += a0[j] * a0[j] + a1[j] * a1[j];
            ushort8 pk;
#pragma unroll
            for (int j = 0; j < 4; j++) {
                pk[j] = f2bf(a0[j]);
                pk[j + 4] = f2bf(a1[j]);
            }
            *(ushort8*)&Ast[lrow][8 * o] = pk;
        }
        const int bn = tid >> 1;
#pragma unroll
        for (int kk = 0; kk < 4; kk++) {
            const int o = (tid & 1) + 2 * kk;
            *(ushort8*)&Bst[bn][8 * o] =
                *(const ushort8*)(Wt + (size_t)bn * K + k0 + 8 * o);
        }
        __syncthreads();
#pragma unroll
        for (int jj = 0; jj < 2; jj++) {
            bf16x8 af = *(const bf16x8*)&Ast[16 * w + m][8 * q + 32 * jj];
#pragma unroll
            for (int t = 0; t < 8; t++) {
                bf16x8 bfv = *(const bf16x8*)&Bst[16 * t + m][8 * q + 32 * jj];
                acc[t] = __builtin_amdgcn_mfma_f32_16x16x32_bf16(af, bfv,
                                                                 acc[t], 0, 0,
                                                                 0);
            }
        }
    }

    sumsq += __shfl_xor(sumsq, 1);
    sumsq += __shfl_xor(sumsq, 2);
    if (lq == 0) rn_s[lrow] = 1.0f / fmaxf(sqrtf(sumsq), 1e-12f);
    __syncthreads();

    float bb[8], gg[8], ee[8];
#pragma unroll
    for (int t = 0; t < 8; t++) {
        bb[t] = bias[16 * t + m];
        gg[t] = g[16 * t + m];
        ee[t] = be[16 * t + m];
    }
#pragma unroll
    for (int r = 0; r < 4; r++) {
        const int lrow2 = 16 * w + 4 * q + r;
        const float rn = rn_s[lrow2];
        float s1 = 0.f, s2 = 0.f;
#pragma unroll
        for (int t = 0; t < 8; t++) {
            float y = fmaf(acc[t][r], rn, bb[t]);
            s1 += y;
            s2 = fmaf(y, y, s2);
        }
#pragma unroll
        for (int mask = 1; mask <= 8; mask <<= 1) {
            s1 += __shfl_xor(s1, mask);
            s2 += __shfl_xor(s2, mask);
        }
        const float mean = s1 * (1.0f / 128.0f);
        const float var = fmaxf(s2 * (1.0f / 128.0f) - mean * mean, 0.0f);
        const float rstd = rsqrtf(var + 1e-5f);
        const int grow = row0 + lrow2;
        if (grow < M) {
            // sliced write: feature 16t+m -> slice t, idx m
#pragma unroll
            for (int t = 0; t < 8; t++) {
                float y = fmaf(acc[t][r], rn, bb[t]);
                float o = fmaxf(fmaf((y - mean) * rstd, gg[t], ee[t]), 0.0f);
                out[((size_t)t * NN + grow) * 16 + m] = f2bf(o);
            }
        }
    }
}

// ---------------------------------------------------------------------------
// Fused tail: per hop, ns_i = relu(LN(z_i @ W_ind_i + b_i)) in-register
// (A-frags direct from sliced global z), transposed through LDS, folded into
// the rel partial acc2 += ns_i @ W_rel[:,k_i].  Never materializes cat.
// ---------------------------------------------------------------------------
__global__ __launch_bounds__(256) void k_tail(
    const unsigned short* __restrict__ z0, const unsigned short* __restrict__ z1,
    const unsigned short* __restrict__ z2, const unsigned short* __restrict__ z3,
    const unsigned short* __restrict__ Wt_ind,  // [4][128][128] n-major
    const float* __restrict__ b_ind, const float* __restrict__ g_ind,
    const float* __restrict__ be_ind,
    const unsigned short* __restrict__ Wt_rel,  // [128][512] n-major
    const float* __restrict__ b_rel, const float* __restrict__ g_rel,
    const float* __restrict__ be_rel, float* __restrict__ out, int M) {
    constexpr int LDW = 136;  // 128 + 8 pad shorts
    __shared__ unsigned short Wst[128][LDW];
    __shared__ unsigned short nsT[64][LDW];

    const int tid = threadIdx.x;
    const int row0 = blockIdx.x * 64;
    const int w = tid >> 6;
    const int lane = tid & 63;
    const int m = lane & 15;
    const int q = lane >> 4;
    const int bn = tid >> 1;

    const unsigned short* zs[4] = {z0, z1, z2, z3};

    f32x4 acc2[8];
#pragma unroll
    for (int t = 0; t < 8; t++) acc2[t] = (f32x4){0.f, 0.f, 0.f, 0.f};

    int arow = row0 + 16 * w + m;  // this lane's A-fragment row (clamped)
    if (arow >= M) arow = M - 1;

#pragma unroll
    for (int hop = 0; hop < NNIE; hop++) {
        __syncthreads();
        // ---- stage W_ind[hop] (B^T, 128x128): 8 octets per thread
        const unsigned short* Wi = Wt_ind + hop * HF * HF;
#pragma unroll
        for (int k = 0; k < 8; k++) {
            const int o = (tid & 1) + 2 * k;
            *(ushort8*)&Wst[bn][8 * o] =
                *(const ushort8*)(Wi + (size_t)bn * HF + 8 * o);
        }
        __syncthreads();
        // ---- MLP GEMM: A direct from sliced global z_hop
        // features [32jj+8q .. +8) -> slice 2jj+(q>>1), idx 8*(q&1)
        f32x4 acc[8];
#pragma unroll
        for (int t = 0; t < 8; t++) acc[t] = (f32x4){0.f, 0.f, 0.f, 0.f};
        const unsigned short* zp = zs[hop];
#pragma unroll
        for (int jj = 0; jj < 4; jj++) {
            bf16x8 af = *(const bf16x8*)(
                zp + ((size_t)(2 * jj + (q >> 1)) * NN + arow) * 16 +
                8 * (q & 1));
#pragma unroll
            for (int t = 0; t < 8; t++) {
                bf16x8 bfv = *(const bf16x8*)&Wst[16 * t + m][8 * q + 32 * jj];
                acc[t] = __builtin_amdgcn_mfma_f32_16x16x32_bf16(af, bfv,
                                                                 acc[t], 0, 0,
                                                                 0);
            }
        }
        // ---- LN + ReLU epilogue -> nsT (row-major tile)
        float bb[8], gg[8], ee[8];
#pragma unroll
        for (int t = 0; t < 8; t++) {
            bb[t] = b_ind[hop * HF + 16 * t + m];
            gg[t] = g_ind[hop * HF + 16 * t + m];
            ee[t] = be_ind[hop * HF + 16 * t + m];
        }
#pragma unroll
        for (int r = 0; r < 4; r++) {
            const int lrow2 = 16 * w + 4 * q + r;
            float s1 = 0.f, s2 = 0.f;
#pragma unroll
            for (int t = 0; t < 8; t++) {
                float y = acc[t][r] + bb[t];
                s1 += y;
                s2 = fmaf(y, y, s2);
            }
#pragma unroll
            for (int mask = 1; mask <= 8; mask <<= 1) {
                s1 += __shfl_xor(s1, mask);
                s2 += __shfl_xor(s2, mask);
            }
            const float mean = s1 * (1.0f / 128.0f);
            const float var = fmaxf(s2 * (1.0f / 128.0f) - mean * mean, 0.0f);
            const float rstd = rsqrtf(var + 1e-5f);
#pragma unroll
            for (int t = 0; t < 8; t++) {
                float y = acc[t][r] + bb[t];
                float o = fmaxf(fmaf((y - mean) * rstd, gg[t], ee[t]), 0.0f);
                nsT[lrow2][16 * t + m] = f2bf(o);
            }
        }
        __syncthreads();  // nsT visible; Wst free for rel chunk
        // ---- stage W_rel k-chunk hop (B^T rows, k = 128*hop..+127)
#pragma unroll
        for (int k = 0; k < 8; k++) {
            const int o = (tid & 1) + 2 * k;
            *(ushort8*)&Wst[bn][8 * o] =
                *(const ushort8*)(Wt_rel + (size_t)bn * (NNIE * HF) +
                                  HF * hop + 8 * o);
        }
        __syncthreads();
        // ---- rel partial GEMM: A from nsT, accumulate acc2
#pragma unroll
        for (int jj = 0; jj < 4; jj++) {
            bf16x8 af = *(const bf16x8*)&nsT[16 * w + m][8 * q + 32 * jj];
#pragma unroll
            for (int t = 0; t < 8; t++) {
                bf16x8 bfv = *(const bf16x8*)&Wst[16 * t + m][8 * q + 32 * jj];
                acc2[t] = __builtin_amdgcn_mfma_f32_16x16x32_bf16(af, bfv,
                                                                  acc2[t], 0,
                                                                  0, 0);
            }
        }
    }

    // ---- final epilogue: bias + LN + ReLU -> fp32 out
    float bb[8], gg[8], ee[8];
#pragma unroll
    for (int t = 0; t < 8; t++) {
        bb[t] = b_rel[16 * t + m];
        gg[t] = g_rel[16 * t + m];
        ee[t] = be_rel[16 * t + m];
    }
#pragma unroll
    for (int r = 0; r < 4; r++) {
        const int lrow2 = 16 * w + 4 * q + r;
        float s1 = 0.f, s2 = 0.f;
#pragma unroll
        for (int t = 0; t < 8; t++) {
            float y = acc2[t][r] + bb[t];
            s1 += y;
            s2 = fmaf(y, y, s2);
        }
#pragma unroll
        for (int mask = 1; mask <= 8; mask <<= 1) {
            s1 += __shfl_xor(s1, mask);
            s2 += __shfl_xor(s2, mask);
        }
        const float mean = s1 * (1.0f / 128.0f);
        const float var = fmaxf(s2 * (1.0f / 128.0f) - mean * mean, 0.0f);
        const float rstd = rsqrtf(var + 1e-5f);
        const int grow = row0 + lrow2;
        if (grow < M) {
#pragma unroll
            for (int t = 0; t < 8; t++) {
                float y = acc2[t][r] + bb[t];
                float o = fmaxf(fmaf((y - mean) * rstd, gg[t], ee[t]), 0.0f);
                out[(size_t)grow * HF + 16 * t + m] = o;
            }
        }
    }
}

// ---------------------------------------------------------------------------
extern "C" void kernel_launch(void* const* d_in, const int* in_sizes, int n_in,
                              void* d_out, int out_size, void* d_ws,
                              size_t ws_size, hipStream_t stream) {
    const int* ei = (const int*)d_in[0];          // [2, E]
    const float* feats = (const float*)d_in[1];   // [N, 512]
    const float* W_uni = (const float*)d_in[2];   // [512,128]
    const float* b_uni = (const float*)d_in[3];
    const float* g_uni = (const float*)d_in[4];
    const float* be_uni = (const float*)d_in[5];
    const float* W_ind = (const float*)d_in[6];   // [4,128,128]
    const float* b_ind = (const float*)d_in[7];
    const float* g_ind = (const float*)d_in[8];
    const float* be_ind = (const float*)d_in[9];
    const float* W_rel = (const float*)d_in[10];  // [512,128]
    const float* b_rel = (const float*)d_in[11];
    const float* g_rel = (const float*)d_in[12];
    const float* be_rel = (const float*)d_in[13];
    float* out = (float*)d_out;

    char* p = (char*)d_ws;
    auto alloc = [&](size_t bytes) {
        void* r = (void*)p;
        p += (bytes + 255) & ~(size_t)255;
        return r;
    };
    int* deg = (int*)alloc(NN * 4);
    int* cursor = (int*)alloc(NN * 4);
    int* off = (int*)alloc((NN + 1) * 4);
    int* bsum = (int*)alloc(1024 * 4);
    int2* es = (int2*)alloc((size_t)NE * 8);
    float* dinv = (float*)alloc(NN * 4);
    unsigned short* Wt_uni = (unsigned short*)alloc(128 * FE * 2);
    unsigned short* Wt_rel = (unsigned short*)alloc(128 * (NNIE * HF) * 2);
    unsigned short* Wt_ind = (unsigned short*)alloc(NNIE * HF * HF * 2);
    unsigned short* h = (unsigned short*)alloc((size_t)NN * HF * 2);
    unsigned short* za = (unsigned short*)alloc((size_t)NN * HF * 2);
    unsigned short* zb = (unsigned short*)alloc((size_t)NN * HF * 2);
    unsigned short* zc = (unsigned short*)alloc((size_t)NN * HF * 2);

    const int gE = (NE + 255) / 256;
    const int gN = (NN + 255) / 256;
    const int gGemm = (NN + 63) / 64;
    const int gSpmm = ((NN + 31) / 32) * 8;  // 8 slices x node chunks of 32
    const int nbScan = (NN + 1023) / 1024;
    const int* erow = ei;
    const int* ecol = ei + NE;

    // graph prep
    k_zero<<<gN, 256, 0, stream>>>(deg, cursor, NN);
    k_count<<<gE, 256, 0, stream>>>(erow, deg, NE);
    k_scan1<<<nbScan, 1024, 0, stream>>>(deg, off, bsum, dinv, NN);
    k_scan2<<<1, 1024, 0, stream>>>(bsum, nbScan, off + NN);
    k_scan3<<<gN, 256, 0, stream>>>(off, bsum, NN);
    k_fill<<<gE, 256, 0, stream>>>(erow, ecol, dinv, off, cursor, es, NE);

    // weight transpose+cvt
    k_wt_all<<<(196608 + 255) / 256, 256, 0, stream>>>(W_uni, W_rel, W_ind,
                                                       Wt_uni, Wt_rel, Wt_ind);

    // unified transform: h = relu(LN(normalize(x) @ W_uni + b))  (sliced out)
    gemm_uni<<<gGemm, 256, 0, stream>>>(feats, Wt_uni, b_uni, g_uni, be_uni, h,
                                        NN);
    // hops (sliced in/out)
    k_spmm<<<gSpmm, 256, 0, stream>>>(h, za, off, es, dinv, NN);
    k_spmm<<<gSpmm, 256, 0, stream>>>(za, zb, off, es, dinv, NN);
    k_spmm<<<gSpmm, 256, 0, stream>>>(zb, zc, off, es, dinv, NN);

    // fused 4x MLP + relation network
    k_tail<<<gGemm, 256, 0, stream>>>(h, za, zb, zc, Wt_ind, b_ind, g_ind,
                                      be_ind, Wt_rel, b_rel, g_rel, be_rel,
                                      out, NN);
}